// Round 11
// baseline (253.629 us; speedup 1.0000x reference)
//
#include <hip/hip_runtime.h>

// ---------------------------------------------------------------------------
// CodecTransformerLayer on MI355X (gfx950).  fp32 inputs (sniff-confirmed),
// bf16 internal compute.  Round 11:
//  * LDS swizzle fixed everywhere: f(row) = (row>>2)&3 (was row&3, which made
//    lanes qr=0,4,8,12 collide -> 4-way bank conflict on every ds_read_b128).
//  * Column-ownership XCD remap generalized (cpx = gridDim.x/8), enabled on
//    QKV / wo / w2-splitK (B panels L2-resident per XCD).
// B=2 S=2048 D=1024 H=16 KVH=8 hd=64 HIDDEN=4096 WINDOW=512
// ---------------------------------------------------------------------------

typedef __bf16 bf16;
typedef __attribute__((ext_vector_type(8))) __bf16 bf16x8;
typedef __attribute__((ext_vector_type(4))) float f32x4;
typedef __attribute__((ext_vector_type(4))) short s16x4;

#define MFMA16(a, b, c) __builtin_amdgcn_mfma_f32_16x16x32_bf16(a, b, c, 0, 0, 0)

__device__ __forceinline__ void gload_lds16(const bf16* g, bf16* l) {
    __builtin_amdgcn_global_load_lds(
        (const __attribute__((address_space(1))) unsigned int*)g,
        (__attribute__((address_space(3))) unsigned int*)l, 16, 0, 0);
}

// ---------------------------------------------------------------------------
__global__ void sniff_kernel(const unsigned short* __restrict__ x, int* __restrict__ flag) {
    __shared__ int s;
    if (threadIdx.x == 0) s = 0;
    __syncthreads();
    int bad = 0;
#pragma unroll
    for (int i = 0; i < 16; ++i) {
        const unsigned short u = x[threadIdx.x * 16 + i];
        const int e = (u >> 7) & 0xFF;
        if (e >= 135) bad = 1;
    }
    if (bad) atomicOr(&s, 1);
    __syncthreads();
    if (threadIdx.x == 0) flag[0] = s;
}

// ---------------------------------------------------------------------------
// Weight gather -> contiguous bf16.  seg map (elements):
// wq[0) wk[1048576) wv[1572864) wo[2097152) w1[3145728) w3[7340032)
// w2[11534336) end 15728640
// ---------------------------------------------------------------------------
__global__ void convert_all_kernel(const void* __restrict__ wq, const void* __restrict__ wk,
                                   const void* __restrict__ wv, const void* __restrict__ wo,
                                   const void* __restrict__ w1, const void* __restrict__ w3,
                                   const void* __restrict__ w2, bf16* __restrict__ dst,
                                   const int* __restrict__ flag) {
    const long e = ((long)blockIdx.x * 256 + threadIdx.x) * 4;
    const void* src; long off;
    if      (e < 1048576)  { src = wq; off = 0; }
    else if (e < 1572864)  { src = wk; off = 1048576; }
    else if (e < 2097152)  { src = wv; off = 1572864; }
    else if (e < 3145728)  { src = wo; off = 2097152; }
    else if (e < 7340032)  { src = w1; off = 3145728; }
    else if (e < 11534336) { src = w3; off = 7340032; }
    else                   { src = w2; off = 11534336; }
    if (flag[0] != 0) {
        const f32x4 v = *(const f32x4*)((const float*)src + (e - off));
        bf16 tmp[4];
#pragma unroll
        for (int j = 0; j < 4; ++j) tmp[j] = (bf16)v[j];
        *(s16x4*)(dst + e) = *(s16x4*)tmp;
    } else {
        *(s16x4*)(dst + e) = *(const s16x4*)((const short*)src + (e - off));
    }
}

// ---------------------------------------------------------------------------
// LayerNorm over last dim W (1024 or 512), one 128-thread block per row.
// ---------------------------------------------------------------------------
__global__ void ln_kernel(const void* __restrict__ in, const void* __restrict__ w,
                          bf16* __restrict__ out, int W, float eps,
                          const int* __restrict__ flag, int in_flv, int w_flv) {
    const int row = blockIdx.x, t = threadIdx.x;
    const int nch = W >> 3;
    const bool act = t < nch;
    const bool f32 = flag[0] != 0;
    float v[8];
    float s = 0.f, s2 = 0.f;
    if (act) {
        if (in_flv && f32) {
            const float* rp = (const float*)in + (size_t)row * W + t * 8;
            const f32x4 a = *(const f32x4*)rp, b = *(const f32x4*)(rp + 4);
#pragma unroll
            for (int j = 0; j < 4; ++j) { v[j] = a[j]; v[4 + j] = b[j]; }
        } else {
            const bf16x8 xv = *(const bf16x8*)((const bf16*)in + (size_t)row * W + t * 8);
#pragma unroll
            for (int j = 0; j < 8; ++j) v[j] = (float)xv[j];
        }
#pragma unroll
        for (int j = 0; j < 8; ++j) { s += v[j]; s2 += v[j] * v[j]; }
    }
#pragma unroll
    for (int off = 32; off; off >>= 1) { s += __shfl_xor(s, off); s2 += __shfl_xor(s2, off); }
    __shared__ float red[4];
    if ((t & 63) == 0) { red[(t >> 6) * 2] = s; red[(t >> 6) * 2 + 1] = s2; }
    __syncthreads();
    const float fs = red[0] + red[2], fs2 = red[1] + red[3];
    const float inw = 1.f / (float)W;
    const float mean = fs * inw;
    const float var = fs2 * inw - mean * mean;
    const float rstd = rsqrtf(var + eps);
    if (act) {
        float wv8[8];
        if (w_flv && f32) {
            const float* wp = (const float*)w + t * 8;
            const f32x4 a = *(const f32x4*)wp, b = *(const f32x4*)(wp + 4);
#pragma unroll
            for (int j = 0; j < 4; ++j) { wv8[j] = a[j]; wv8[4 + j] = b[j]; }
        } else {
            const bf16x8 ww = *(const bf16x8*)((const bf16*)w + t * 8);
#pragma unroll
            for (int j = 0; j < 8; ++j) wv8[j] = (float)ww[j];
        }
        bf16x8 ov;
#pragma unroll
        for (int j = 0; j < 8; ++j) ov[j] = (bf16)((v[j] - mean) * rstd * wv8[j]);
        *(bf16x8*)(out + (size_t)row * W + t * 8) = ov;
    }
}

// ---------------------------------------------------------------------------
// Split-K reduce: out = x1 + (p0+p1)*scale[col].  p bf16 [2][4096][1024].
// ---------------------------------------------------------------------------
__global__ void reduce_k(const bf16* __restrict__ p, const bf16* __restrict__ x1,
                         const void* __restrict__ scale, void* __restrict__ out,
                         const int* __restrict__ flag) {
    const bool f32 = flag[0] != 0;
    const size_t i8 = ((size_t)blockIdx.x * 256 + threadIdx.x) * 8;
    const int col = (int)(i8 & 1023);
    const bf16x8 a = *(const bf16x8*)(p + i8);
    const bf16x8 b = *(const bf16x8*)(p + 4194304 + i8);
    const bf16x8 r = *(const bf16x8*)(x1 + i8);
    float sc8[8];
    if (f32) {
        const f32x4 s0 = *(const f32x4*)((const float*)scale + col);
        const f32x4 s1 = *(const f32x4*)((const float*)scale + col + 4);
#pragma unroll
        for (int j = 0; j < 4; ++j) { sc8[j] = s0[j]; sc8[4 + j] = s1[j]; }
    } else {
        const bf16x8 sb = *(const bf16x8*)((const bf16*)scale + col);
#pragma unroll
        for (int j = 0; j < 8; ++j) sc8[j] = (float)sb[j];
    }
    float o[8];
#pragma unroll
    for (int j = 0; j < 8; ++j)
        o[j] = (float)r[j] + ((float)a[j] + (float)b[j]) * sc8[j];
    if (f32) {
        f32x4 o0, o1;
#pragma unroll
        for (int j = 0; j < 4; ++j) { o0[j] = o[j]; o1[j] = o[4 + j]; }
        *(f32x4*)((float*)out + i8) = o0;
        *(f32x4*)((float*)out + i8 + 4) = o1;
    } else {
        bf16x8 ov;
#pragma unroll
        for (int j = 0; j < 8; ++j) ov[j] = (bf16)o[j];
        *(bf16x8*)((bf16*)out + i8) = ov;
    }
}

// ---------------------------------------------------------------------------
// Pipelined GEMM  C[M,N] = A[M,K] * B[N,K]^T.  128x128 tile, BK=32, 8 waves
// (2Mx4N), NBUF-deep counted-vmcnt pipeline, chunk-XOR LDS swizzle with
// f(row)=(row>>2)&3 (2-way residual = free).  SWZ=1: column-ownership XCD
// remap (cpx = gridDim.x/8 column panels per XCD, B panels L2-resident).
// SPLITK=1: blockIdx.z selects K half.  Epilogues: 0 plain; 1 res+acc*scale;
// 3 silu(res)*acc; 4 QKV split.
// ---------------------------------------------------------------------------
template <int EPI, int NBUF, int SWZ, int SPLITK>
__global__ __launch_bounds__(512, 4)
void gemm2(const bf16* __restrict__ A, const bf16* __restrict__ B,
           void* __restrict__ Cout, const void* __restrict__ res,
           const void* __restrict__ scale, int M, int N, int K,
           const int* __restrict__ flag, int res_flv, int out_flv) {
    __shared__ bf16 LDS[NBUF * 8192];
    const bool f32 = flag[0] != 0;
    const int t = threadIdx.x;
    const int wv = t >> 6, ln = t & 63;
    const int qr = ln & 15, g = ln >> 4;
    const int wr = wv >> 2, wc = wv & 3;
    int bx = blockIdx.x, by = blockIdx.y;
    if (SWZ) {   // column-ownership: XCD owns cpx column panels
        const int cpx = gridDim.x >> 3;
        const int bid = by * gridDim.x + bx;
        const int xcd = bid & 7, m = bid >> 3;
        bx = xcd * cpx + (m % cpx);
        by = m / cpx;
    }
    const int row0 = by * 128, col0 = bx * 128;

    const int Koff = SPLITK ? (int)blockIdx.z * (K >> 1) : 0;
    const int Keff = SPLITK ? (K >> 1) : K;
    if (SPLITK) Cout = (void*)((bf16*)Cout + (size_t)blockIdx.z * ((size_t)M * N));

    f32x4 acc[4][2] = {};

    const int cx = ((t & 3) ^ ((t >> 4) & 3)) * 8;   // f(row)=(row>>2)&3, row=t>>2
    const bf16* aSrc = A + (size_t)(row0 + (t >> 2)) * K + Koff + cx;
    const bf16* bSrc = B + (size_t)(col0 + (t >> 2)) * K + Koff + cx;
    const int gx8 = (g ^ ((qr >> 2) & 3)) * 8;       // swizzled read chunk
    const int NIT = Keff >> 5;

#define STAGE(bi, k0)                                              \
    do {                                                           \
        bf16* lb = LDS + (bi) * 8192 + wv * 512;                   \
        gload_lds16(aSrc + (k0), lb);                              \
        gload_lds16(bSrc + (k0), lb + 4096);                       \
    } while (0)

#pragma unroll
    for (int pb = 0; pb < NBUF - 1; ++pb) STAGE(pb, pb * 32);
    if constexpr (NBUF == 3) asm volatile("s_waitcnt vmcnt(2)" ::: "memory");
    else                     asm volatile("s_waitcnt vmcnt(6)" ::: "memory");
    __builtin_amdgcn_s_barrier();
    __builtin_amdgcn_sched_barrier(0);

    int cur = 0, sb = NBUF - 1;
    for (int it = 0; it < NIT; ++it) {
        const bool more = (it + NBUF - 1) < NIT;
        if (more) STAGE(sb, (it + NBUF - 1) * 32);
        const bf16* bufA = LDS + cur * 8192;
        const bf16* bufB = bufA + 4096;
        bf16x8 af[4], bfr[2];
#pragma unroll
        for (int i = 0; i < 4; ++i)
            af[i] = *(const bf16x8*)&bufA[(wr * 64 + i * 16 + qr) * 32 + gx8];
#pragma unroll
        for (int j = 0; j < 2; ++j)
            bfr[j] = *(const bf16x8*)&bufB[(wc * 32 + j * 16 + qr) * 32 + gx8];
#pragma unroll
        for (int i = 0; i < 4; ++i)
#pragma unroll
            for (int j = 0; j < 2; ++j)
                acc[i][j] = MFMA16(af[i], bfr[j], acc[i][j]);
        if (more) {
            if constexpr (NBUF == 3) asm volatile("s_waitcnt vmcnt(2)" ::: "memory");
            else                     asm volatile("s_waitcnt vmcnt(6)" ::: "memory");
        } else {
            asm volatile("s_waitcnt vmcnt(0)" ::: "memory");
        }
        __builtin_amdgcn_s_barrier();
        __builtin_amdgcn_sched_barrier(0);
        cur = cur + 1 == NBUF ? 0 : cur + 1;
        sb  = sb + 1 == NBUF ? 0 : sb + 1;
    }
#undef STAGE

#pragma unroll
    for (int i = 0; i < 4; ++i) {
#pragma unroll
        for (int j = 0; j < 2; ++j) {
            const int rr0 = row0 + wr * 64 + i * 16 + g * 4;  // C/D row=(l>>4)*4+r
            const int cc  = col0 + wc * 32 + j * 16 + qr;     //     col=l&15
            if (EPI == 4) {
                if (cc < 1024) {                 // q
#pragma unroll
                    for (int r = 0; r < 4; ++r)
                        ((bf16*)Cout)[(size_t)(rr0 + r) * 1024 + cc] = (bf16)acc[i][j][r];
                } else if (cc < 1536) {          // k
#pragma unroll
                    for (int r = 0; r < 4; ++r)
                        ((bf16*)res)[(size_t)(rr0 + r) * 512 + (cc - 1024)] = (bf16)acc[i][j][r];
                } else {                         // v transposed bf16: Vt[b][kvh][d][s]
                    const int kv = cc - 1536, kvh = kv >> 6, d = kv & 63;
                    const int bb = rr0 >> 11, s0 = rr0 & 2047;
                    bf16 tmp[4];
#pragma unroll
                    for (int r = 0; r < 4; ++r) tmp[r] = (bf16)acc[i][j][r];
                    *(s16x4*)((bf16*)scale + (((size_t)bb * 8 + kvh) * 64 + d) * 2048 + s0) = *(s16x4*)tmp;
                }
            } else {
                float scv = 0.f;
                if (EPI == 1)
                    scv = f32 ? ((const float*)scale)[cc] : (float)((const bf16*)scale)[cc];
#pragma unroll
                for (int r = 0; r < 4; ++r) {
                    const size_t idx = (size_t)(rr0 + r) * N + cc;
                    float vv = acc[i][j][r];
                    if (EPI == 1) {
                        const float rv = (res_flv && f32) ? ((const float*)res)[idx]
                                                          : (float)((const bf16*)res)[idx];
                        vv = rv + vv * scv;
                    }
                    if (EPI == 3) {
                        const float uv = (float)((const bf16*)res)[idx];
                        vv = uv / (1.f + __expf(-uv)) * vv;
                    }
                    if (out_flv && f32) ((float*)Cout)[idx] = vv;
                    else                ((bf16*)Cout)[idx] = (bf16)vv;
                }
            }
        }
    }
}

// ---------------------------------------------------------------------------
// gemm_w13: fused SwiGLU up-projection.  C = silu(A@B1^T) * (A@B3^T).
// 128x128 tile, BK=32, 8 waves (2Mx4N), 3-buffer counted-vmcnt pipeline,
// shared A staging, fixed chunk-XOR swizzle, column-ownership XCD remap
// (4 col panels/XCD, B1+B3 2 MB L2-resident), swapped-operand MFMA ->
// s16x4 stores.
// ---------------------------------------------------------------------------
__global__ __launch_bounds__(512, 4)
void gemm_w13(const bf16* __restrict__ A, const bf16* __restrict__ B1,
              const bf16* __restrict__ B3, bf16* __restrict__ C,
              int M, int N, int K) {
    __shared__ bf16 LDS[3 * 12288];      // per buf: A 8KB | B1 8KB | B3 8KB
    const int t = threadIdx.x;
    const int wv = t >> 6, ln = t & 63;
    const int qr = ln & 15, g = ln >> 4;
    const int wr = wv >> 2, wc = wv & 3;
    int bx, by;
    {   // column-ownership XCD remap (grid 32x32, bijective)
        const int bid = blockIdx.y * gridDim.x + blockIdx.x;
        const int xcd = bid & 7, m = bid >> 3;
        bx = xcd * 4 + (m & 3);
        by = m >> 2;
    }
    const int row0 = by * 128, col0 = bx * 128;

    f32x4 acc1[4][2] = {}, acc3[4][2] = {};

    const int cx = ((t & 3) ^ ((t >> 4) & 3)) * 8;   // f(row)=(row>>2)&3
    const bf16* aSrc  = A  + (size_t)(row0 + (t >> 2)) * K + cx;
    const bf16* b1Src = B1 + (size_t)(col0 + (t >> 2)) * K + cx;
    const bf16* b3Src = B3 + (size_t)(col0 + (t >> 2)) * K + cx;
    const int gx8 = (g ^ ((qr >> 2) & 3)) * 8;
    const int NIT = K >> 5;

#define STAGEW(bi, k0)                                             \
    do {                                                           \
        bf16* lb = LDS + (bi) * 12288 + wv * 512;                  \
        gload_lds16(aSrc + (k0), lb);                              \
        gload_lds16(b1Src + (k0), lb + 4096);                      \
        gload_lds16(b3Src + (k0), lb + 8192);                      \
    } while (0)

    STAGEW(0, 0);
    STAGEW(1, 32);
    asm volatile("s_waitcnt vmcnt(3)" ::: "memory");
    __builtin_amdgcn_s_barrier();
    __builtin_amdgcn_sched_barrier(0);

    int cur = 0, sb = 2;
    for (int it = 0; it < NIT; ++it) {
        const bool more = (it + 2) < NIT;
        if (more) STAGEW(sb, (it + 2) * 32);
        const bf16* bufA  = LDS + cur * 12288;
        const bf16* bufB1 = bufA + 4096;
        const bf16* bufB3 = bufA + 8192;
        bf16x8 af[4], b1f[2], b3f[2];
#pragma unroll
        for (int i = 0; i < 4; ++i)
            af[i] = *(const bf16x8*)&bufA[(wr * 64 + i * 16 + qr) * 32 + gx8];
#pragma unroll
        for (int j = 0; j < 2; ++j) {
            b1f[j] = *(const bf16x8*)&bufB1[(wc * 32 + j * 16 + qr) * 32 + gx8];
            b3f[j] = *(const bf16x8*)&bufB3[(wc * 32 + j * 16 + qr) * 32 + gx8];
        }
#pragma unroll
        for (int i = 0; i < 4; ++i)
#pragma unroll
            for (int j = 0; j < 2; ++j) {
                acc1[i][j] = MFMA16(b1f[j], af[i], acc1[i][j]);   // swapped
                acc3[i][j] = MFMA16(b3f[j], af[i], acc3[i][j]);   // swapped
            }
        if (more) asm volatile("s_waitcnt vmcnt(3)" ::: "memory");
        else      asm volatile("s_waitcnt vmcnt(0)" ::: "memory");
        __builtin_amdgcn_s_barrier();
        __builtin_amdgcn_sched_barrier(0);
        cur = cur == 2 ? 0 : cur + 1;
        sb  = sb  == 2 ? 0 : sb  + 1;
    }
#undef STAGEW

    // swapped C/D: row = row0+wr*64+i*16+qr, cols = col0+wc*32+j*16+g*4+r
#pragma unroll
    for (int i = 0; i < 4; ++i) {
        const int row = row0 + wr * 64 + i * 16 + qr;
#pragma unroll
        for (int j = 0; j < 2; ++j) {
            const int col = col0 + wc * 32 + j * 16 + g * 4;
            const size_t idx = (size_t)row * N + col;
            bf16 tmp[4];
#pragma unroll
            for (int r = 0; r < 4; ++r) {
                const float u1 = acc1[i][j][r];
                const float u3 = acc3[i][j][r];
                tmp[r] = (bf16)(u1 / (1.f + __expf(-u1)) * u3);
            }
            *(s16x4*)(C + idx) = *(s16x4*)tmp;
        }
    }
}

// ---------------------------------------------------------------------------
// Windowed-ALiBi GQA flash attention (round-8 structure; V swizzle fixed to
// f(row)=(row>>2)&3 on both staging and read sides).
// ---------------------------------------------------------------------------
__global__ __launch_bounds__(256)
void attn_kernel(const bf16* __restrict__ qn, const bf16* __restrict__ kn,
                 const bf16* __restrict__ vt, bf16* __restrict__ aout) {
    __shared__ bf16 SH[3 * 4096];      // buf: K [32 key][64 hd] | V [64 d][32 key]
    const int t = threadIdx.x, wv = t >> 6, ln = t & 63;
    const int qr = ln & 15, g = ln >> 4;
    const int h = blockIdx.y, b = blockIdx.z, kvh = h >> 1;
    const int q0blk = blockIdx.x * 64;
    const int qa = q0blk + wv * 16 + qr;
    const float slope = exp2f(-0.5f * (float)(h + 1));

    const bf16* qrow = qn + ((size_t)(b * 2048 + qa)) * 1024 + h * 64;
    const bf16x8 qb0 = *(const bf16x8*)(qrow + g * 8);
    const bf16x8 qb1 = *(const bf16x8*)(qrow + 32 + g * 8);

    const bf16* kbase = kn + (size_t)b * 2048 * 512 + kvh * 64;
    const bf16* vbase = vt + ((size_t)(b * 8 + kvh) * 64) * 2048;
    const int krow_l = t >> 3;
    const int kcsrc  = (t & 7) ^ ((t >> 3) & 7);
    const int vd     = t >> 2;
    const int vcsrc  = (t & 3) ^ ((t >> 4) & 3);     // f(row)=(row>>2)&3
    const bf16* kgsrc = kbase + kcsrc * 8;
    const bf16* vgsrc = vbase + (size_t)vd * 2048;
    bf16* lK0 = SH + wv * 512;
    bf16* lV0 = SH + 2048 + wv * 512;

#define STAGE_T(kts, bi)                                           \
    do {                                                           \
        int ksrc = (kts) + krow_l;                                 \
        ksrc = ksrc > 2047 ? 2047 : ksrc;                          \
        gload_lds16(kgsrc + (size_t)ksrc * 512, lK0 + (bi) * 4096);\
        int vsrc = (kts) + vcsrc * 8;                              \
        vsrc = vsrc > 2040 ? 2040 : vsrc;                          \
        gload_lds16(vgsrc + vsrc, lV0 + (bi) * 4096);              \
    } while (0)

    STAGE_T(q0blk, 0);
    STAGE_T(q0blk + 32, 1);
    asm volatile("s_waitcnt vmcnt(2)" ::: "memory");
    __builtin_amdgcn_s_barrier();
    __builtin_amdgcn_sched_barrier(0);

    f32x4 o[4] = {};
    float mrun = -1e29f, lsum = 0.f;
    int cur = 0, sb = 2;

    for (int it = 0; it < 18; ++it) {
        const int kt = q0blk + it * 32;
        const bool more = (it + 2) < 18;
        if (more) STAGE_T(kt + 64, sb);
        const bf16* Kb = SH + cur * 4096;
        const bf16* Vb = Kb + 2048;

        f32x4 sc[2] = {f32x4{0, 0, 0, 0}, f32x4{0, 0, 0, 0}};
#pragma unroll
        for (int ks = 0; ks < 2; ++ks) {
            const int lrow = ks * 16 + qr;
            const int sw = (lrow & 7) * 8;
            sc[ks] = MFMA16(*(const bf16x8*)&Kb[lrow * 64 + (((g) * 8) ^ sw)],        qb0, sc[ks]);
            sc[ks] = MFMA16(*(const bf16x8*)&Kb[lrow * 64 + (((4 + g) * 8) ^ sw)],    qb1, sc[ks]);
        }
        float s[2][4], p[2][4];
        float tmax = -1e30f;
#pragma unroll
        for (int ks = 0; ks < 2; ++ks)
#pragma unroll
            for (int r = 0; r < 4; ++r) {
                const int key = kt + ks * 16 + g * 4 + r;
                const int dist = key - qa;
                const bool valid = (dist >= 0) && (dist <= 512) && (key < 2048);
                const float sv = valid ? sc[ks][r] * 0.125f - slope * (float)dist : -1e30f;
                s[ks][r] = sv;
                tmax = fmaxf(tmax, sv);
            }
        tmax = fmaxf(tmax, __shfl_xor(tmax, 16));
        tmax = fmaxf(tmax, __shfl_xor(tmax, 32));
        const float mnew = fmaxf(mrun, tmax);
        const float alpha = __expf(mrun - mnew);
        mrun = mnew;
        float ps = 0.f;
#pragma unroll
        for (int ks = 0; ks < 2; ++ks)
#pragma unroll
            for (int r = 0; r < 4; ++r) { p[ks][r] = __expf(s[ks][r] - mnew); ps += p[ks][r]; }
        lsum = lsum * alpha + ps;
#pragma unroll
        for (int fd = 0; fd < 4; ++fd) o[fd] *= alpha;

        bf16x8 pb;
#pragma unroll
        for (int j = 0; j < 8; ++j) {
            const int srcl = (((2 * g + (j >> 2)) & 3) << 4) | qr;
            const float v0 = __shfl(p[0][j & 3], srcl);
            const float v1 = __shfl(p[1][j & 3], srcl);
            pb[j] = (bf16)((g & 2) ? v1 : v0);
        }
#pragma unroll
        for (int fd = 0; fd < 4; ++fd) {
            const int d = fd * 16 + qr;
            const bf16x8 va = *(const bf16x8*)&Vb[d * 32 + ((g ^ ((d >> 2) & 3)) * 8)];
            o[fd] = MFMA16(va, pb, o[fd]);
        }

        if (more) asm volatile("s_waitcnt vmcnt(2)" ::: "memory");
        else      asm volatile("s_waitcnt vmcnt(0)" ::: "memory");
        __builtin_amdgcn_s_barrier();
        __builtin_amdgcn_sched_barrier(0);
        cur = cur == 2 ? 0 : cur + 1;
        sb  = sb  == 2 ? 0 : sb  + 1;
    }
#undef STAGE_T

    float lt = lsum + __shfl_xor(lsum, 16);
    lt += __shfl_xor(lt, 32);
    lt = fmaxf(lt, 1e-30f);
    const float inv = 1.f / lt;
    bf16* orow = aout + ((size_t)(b * 2048 + qa)) * 1024 + h * 64;
#pragma unroll
    for (int fd = 0; fd < 4; ++fd) {
        bf16 tmp[4];
#pragma unroll
        for (int r = 0; r < 4; ++r) tmp[r] = (bf16)(o[fd][r] * inv);
        *(s16x4*)(orow + fd * 16 + g * 4) = *(s16x4*)tmp;
    }
}

// ---------------------------------------------------------------------------
extern "C" void kernel_launch(void* const* d_in, const int* in_sizes, int n_in,
                              void* d_out, int out_size, void* d_ws, size_t ws_size,
                              hipStream_t stream) {
    int* flag = (int*)d_ws;
    bf16* base = (bf16*)d_ws + 64;
    bf16* h    = base;                // 4096*1024  (reused as h2)
    bf16* q    = h + 4194304;         // 4096*1024  (x1 after attn)
    bf16* kbuf = q + 4194304;         // 4096*512   (split-K partial base later)
    bf16* vtb  = kbuf + 2097152;      // 2*8*64*2048
    bf16* aout = vtb + 2097152;       // 4096*1024  (kbuf..aout = 2x4194304 span)
    bf16* u    = aout + 4194304;      // 4096*4096  (act)
    bf16* wcv  = u + 16777216;        // 15728640 converted weights (contiguous)

    bf16* woc = wcv + 2097152;
    bf16* w1c = wcv + 3145728;
    bf16* w3c = wcv + 7340032;
    bf16* w2c = wcv + 11534336;

    const dim3 blk(512);
    sniff_kernel<<<1, 256, 0, stream>>>((const unsigned short*)d_in[0], flag);
    convert_all_kernel<<<15360, 256, 0, stream>>>(
        d_in[1], d_in[2], d_in[3], d_in[4], d_in[9], d_in[11], d_in[10], wcv, flag);

    ln_kernel<<<4096, 128, 0, stream>>>(d_in[0], d_in[7], h, 1024, 1e-5f, flag, 1, 1);
    // fused QKV: B = [wq;wk;wv] rows, N=2048.  EPI4: Cout=q, res=kbuf, scale=vtb
    gemm2<4, 3, 1, 0><<<dim3(16, 32), blk, 0, stream>>>(h, wcv, q, kbuf, vtb, 4096, 2048, 1024, flag, 0, 0);
    ln_kernel<<<4096, 128, 0, stream>>>(q, d_in[5], q, 1024, 1e-6f, flag, 0, 1);
    ln_kernel<<<4096, 128, 0, stream>>>(kbuf, d_in[6], kbuf, 512, 1e-6f, flag, 0, 1);
    attn_kernel<<<dim3(32, 16, 2), dim3(256), 0, stream>>>(q, kbuf, vtb, aout);
    // x1 = x + (aout@wo^T)*attn_scale  -> q (bf16)
    gemm2<1, 3, 1, 0><<<dim3(8, 32), blk, 0, stream>>>(aout, woc, q, d_in[0], d_in[12], 4096, 1024, 1024, flag, 1, 0);
    ln_kernel<<<4096, 128, 0, stream>>>(q, d_in[8], h, 1024, 1e-5f, flag, 0, 1);
    // fused SwiGLU up: u = silu(h@w1^T) * (h@w3^T)
    gemm_w13<<<dim3(32, 32), blk, 0, stream>>>(h, w1c, w3c, u, 4096, 4096, 1024);
    // w2 split-K=2: partials (bf16) -> kbuf span, then reduce -> d_out
    gemm2<0, 5, 1, 1><<<dim3(8, 32, 2), blk, 0, stream>>>(u, w2c, kbuf, nullptr, nullptr, 4096, 1024, 4096, flag, 0, 0);
    reduce_k<<<2048, 256, 0, stream>>>(kbuf, q, d_in[13], d_out, flag);
}

// Round 12
// 246.887 us; speedup vs baseline: 1.0273x; 1.0273x over previous
//
#include <hip/hip_runtime.h>

// ---------------------------------------------------------------------------
// CodecTransformerLayer on MI355X (gfx950).  fp32 inputs (sniff-confirmed),
// bf16 internal compute.  Round 12:
//  * Reverted round-11 remap experiment (ownership must follow the LARGER
//    operand: w13 owns B-columns; wo/w2 keep row remap; QKV none).
//  * Attention: 2-heads-per-block K/V sharing (512 thr, 8 waves = 4 q-sub x
//    2 heads; threads 0-255 stage K, 256-511 stage V; vmcnt(1) ledger) —
//    halves staging loads and K/V L2 traffic.
//  * q-norm + k-norm fused into one launch.
// B=2 S=2048 D=1024 H=16 KVH=8 hd=64 HIDDEN=4096 WINDOW=512
// ---------------------------------------------------------------------------

typedef __bf16 bf16;
typedef __attribute__((ext_vector_type(8))) __bf16 bf16x8;
typedef __attribute__((ext_vector_type(4))) float f32x4;
typedef __attribute__((ext_vector_type(4))) short s16x4;

#define MFMA16(a, b, c) __builtin_amdgcn_mfma_f32_16x16x32_bf16(a, b, c, 0, 0, 0)

__device__ __forceinline__ void gload_lds16(const bf16* g, bf16* l) {
    __builtin_amdgcn_global_load_lds(
        (const __attribute__((address_space(1))) unsigned int*)g,
        (__attribute__((address_space(3))) unsigned int*)l, 16, 0, 0);
}

// ---------------------------------------------------------------------------
__global__ void sniff_kernel(const unsigned short* __restrict__ x, int* __restrict__ flag) {
    __shared__ int s;
    if (threadIdx.x == 0) s = 0;
    __syncthreads();
    int bad = 0;
#pragma unroll
    for (int i = 0; i < 16; ++i) {
        const unsigned short u = x[threadIdx.x * 16 + i];
        const int e = (u >> 7) & 0xFF;
        if (e >= 135) bad = 1;
    }
    if (bad) atomicOr(&s, 1);
    __syncthreads();
    if (threadIdx.x == 0) flag[0] = s;
}

// ---------------------------------------------------------------------------
// Weight gather -> contiguous bf16.  seg map (elements):
// wq[0) wk[1048576) wv[1572864) wo[2097152) w1[3145728) w3[7340032)
// w2[11534336) end 15728640
// ---------------------------------------------------------------------------
__global__ void convert_all_kernel(const void* __restrict__ wq, const void* __restrict__ wk,
                                   const void* __restrict__ wv, const void* __restrict__ wo,
                                   const void* __restrict__ w1, const void* __restrict__ w3,
                                   const void* __restrict__ w2, bf16* __restrict__ dst,
                                   const int* __restrict__ flag) {
    const long e = ((long)blockIdx.x * 256 + threadIdx.x) * 4;
    const void* src; long off;
    if      (e < 1048576)  { src = wq; off = 0; }
    else if (e < 1572864)  { src = wk; off = 1048576; }
    else if (e < 2097152)  { src = wv; off = 1572864; }
    else if (e < 3145728)  { src = wo; off = 2097152; }
    else if (e < 7340032)  { src = w1; off = 3145728; }
    else if (e < 11534336) { src = w3; off = 7340032; }
    else                   { src = w2; off = 11534336; }
    if (flag[0] != 0) {
        const f32x4 v = *(const f32x4*)((const float*)src + (e - off));
        bf16 tmp[4];
#pragma unroll
        for (int j = 0; j < 4; ++j) tmp[j] = (bf16)v[j];
        *(s16x4*)(dst + e) = *(s16x4*)tmp;
    } else {
        *(s16x4*)(dst + e) = *(const s16x4*)((const short*)src + (e - off));
    }
}

// ---------------------------------------------------------------------------
// LayerNorm row body (128 threads per row).
// ---------------------------------------------------------------------------
__device__ __forceinline__ void ln_row(const void* in, const void* w, bf16* out,
                                       int row, int W, float eps, bool f32,
                                       int in_flv, int w_flv) {
    const int t = threadIdx.x;
    const int nch = W >> 3;
    const bool act = t < nch;
    float v[8];
    float s = 0.f, s2 = 0.f;
    if (act) {
        if (in_flv && f32) {
            const float* rp = (const float*)in + (size_t)row * W + t * 8;
            const f32x4 a = *(const f32x4*)rp, b = *(const f32x4*)(rp + 4);
#pragma unroll
            for (int j = 0; j < 4; ++j) { v[j] = a[j]; v[4 + j] = b[j]; }
        } else {
            const bf16x8 xv = *(const bf16x8*)((const bf16*)in + (size_t)row * W + t * 8);
#pragma unroll
            for (int j = 0; j < 8; ++j) v[j] = (float)xv[j];
        }
#pragma unroll
        for (int j = 0; j < 8; ++j) { s += v[j]; s2 += v[j] * v[j]; }
    }
#pragma unroll
    for (int off = 32; off; off >>= 1) { s += __shfl_xor(s, off); s2 += __shfl_xor(s2, off); }
    __shared__ float red[4];
    if ((t & 63) == 0) { red[(t >> 6) * 2] = s; red[(t >> 6) * 2 + 1] = s2; }
    __syncthreads();
    const float fs = red[0] + red[2], fs2 = red[1] + red[3];
    const float inw = 1.f / (float)W;
    const float mean = fs * inw;
    const float var = fs2 * inw - mean * mean;
    const float rstd = rsqrtf(var + eps);
    if (act) {
        float wv8[8];
        if (w_flv && f32) {
            const float* wp = (const float*)w + t * 8;
            const f32x4 a = *(const f32x4*)wp, b = *(const f32x4*)(wp + 4);
#pragma unroll
            for (int j = 0; j < 4; ++j) { wv8[j] = a[j]; wv8[4 + j] = b[j]; }
        } else {
            const bf16x8 ww = *(const bf16x8*)((const bf16*)w + t * 8);
#pragma unroll
            for (int j = 0; j < 8; ++j) wv8[j] = (float)ww[j];
        }
        bf16x8 ov;
#pragma unroll
        for (int j = 0; j < 8; ++j) ov[j] = (bf16)((v[j] - mean) * rstd * wv8[j]);
        *(bf16x8*)(out + (size_t)row * W + t * 8) = ov;
    }
}

__global__ void ln_kernel(const void* __restrict__ in, const void* __restrict__ w,
                          bf16* __restrict__ out, int W, float eps,
                          const int* __restrict__ flag, int in_flv, int w_flv) {
    ln_row(in, w, out, blockIdx.x, W, eps, flag[0] != 0, in_flv, w_flv);
}

// fused q-norm (rows 0..4095, W=1024) + k-norm (rows 4096..8191, W=512)
__global__ void ln_qk_kernel(bf16* __restrict__ q, const void* __restrict__ qw,
                             bf16* __restrict__ kbuf, const void* __restrict__ kw,
                             const int* __restrict__ flag) {
    const bool f32 = flag[0] != 0;
    if (blockIdx.x < 4096)
        ln_row(q, qw, q, blockIdx.x, 1024, 1e-6f, f32, 0, 1);
    else
        ln_row(kbuf, kw, kbuf, blockIdx.x - 4096, 512, 1e-6f, f32, 0, 1);
}

// ---------------------------------------------------------------------------
// Split-K reduce: out = x1 + (p0+p1)*scale[col].  p bf16 [2][4096][1024].
// ---------------------------------------------------------------------------
__global__ void reduce_k(const bf16* __restrict__ p, const bf16* __restrict__ x1,
                         const void* __restrict__ scale, void* __restrict__ out,
                         const int* __restrict__ flag) {
    const bool f32 = flag[0] != 0;
    const size_t i8 = ((size_t)blockIdx.x * 256 + threadIdx.x) * 8;
    const int col = (int)(i8 & 1023);
    const bf16x8 a = *(const bf16x8*)(p + i8);
    const bf16x8 b = *(const bf16x8*)(p + 4194304 + i8);
    const bf16x8 r = *(const bf16x8*)(x1 + i8);
    float sc8[8];
    if (f32) {
        const f32x4 s0 = *(const f32x4*)((const float*)scale + col);
        const f32x4 s1 = *(const f32x4*)((const float*)scale + col + 4);
#pragma unroll
        for (int j = 0; j < 4; ++j) { sc8[j] = s0[j]; sc8[4 + j] = s1[j]; }
    } else {
        const bf16x8 sb = *(const bf16x8*)((const bf16*)scale + col);
#pragma unroll
        for (int j = 0; j < 8; ++j) sc8[j] = (float)sb[j];
    }
    float o[8];
#pragma unroll
    for (int j = 0; j < 8; ++j)
        o[j] = (float)r[j] + ((float)a[j] + (float)b[j]) * sc8[j];
    if (f32) {
        f32x4 o0, o1;
#pragma unroll
        for (int j = 0; j < 4; ++j) { o0[j] = o[j]; o1[j] = o[4 + j]; }
        *(f32x4*)((float*)out + i8) = o0;
        *(f32x4*)((float*)out + i8 + 4) = o1;
    } else {
        bf16x8 ov;
#pragma unroll
        for (int j = 0; j < 8; ++j) ov[j] = (bf16)o[j];
        *(bf16x8*)((bf16*)out + i8) = ov;
    }
}

// ---------------------------------------------------------------------------
// Pipelined GEMM  C[M,N] = A[M,K] * B[N,K]^T.  128x128 tile, BK=32, 8 waves
// (2Mx4N), NBUF-deep counted-vmcnt pipeline, chunk-XOR LDS swizzle.
// SWZ=1: row-ownership XCD remap (round-10 form).  SPLITK=1: blockIdx.z
// selects K half.  Epilogues: 0 plain; 1 res+acc*scale; 3 silu(res)*acc;
// 4 QKV split.
// ---------------------------------------------------------------------------
template <int EPI, int NBUF, int SWZ, int SPLITK>
__global__ __launch_bounds__(512, 4)
void gemm2(const bf16* __restrict__ A, const bf16* __restrict__ B,
           void* __restrict__ Cout, const void* __restrict__ res,
           const void* __restrict__ scale, int M, int N, int K,
           const int* __restrict__ flag, int res_flv, int out_flv) {
    __shared__ bf16 LDS[NBUF * 8192];
    const bool f32 = flag[0] != 0;
    const int t = threadIdx.x;
    const int wv = t >> 6, ln = t & 63;
    const int qr = ln & 15, g = ln >> 4;
    const int wr = wv >> 2, wc = wv & 3;
    int bx = blockIdx.x, by = blockIdx.y;
    if (SWZ) {   // row-ownership remap (round-10 verified)
        const int bid = by * gridDim.x + bx;
        const int g8 = bid & 7, m = bid >> 3;
        bx = m % gridDim.x;
        by = g8 + 8 * (m / gridDim.x);
    }
    const int row0 = by * 128, col0 = bx * 128;

    const int Koff = SPLITK ? (int)blockIdx.z * (K >> 1) : 0;
    const int Keff = SPLITK ? (K >> 1) : K;
    if (SPLITK) Cout = (void*)((bf16*)Cout + (size_t)blockIdx.z * ((size_t)M * N));

    f32x4 acc[4][2] = {};

    const int cx = ((t & 3) ^ ((t >> 2) & 3)) * 8;
    const bf16* aSrc = A + (size_t)(row0 + (t >> 2)) * K + Koff + cx;
    const bf16* bSrc = B + (size_t)(col0 + (t >> 2)) * K + Koff + cx;
    const int gx8 = (g ^ (qr & 3)) * 8;              // swizzled read chunk
    const int NIT = Keff >> 5;

#define STAGE(bi, k0)                                              \
    do {                                                           \
        bf16* lb = LDS + (bi) * 8192 + wv * 512;                   \
        gload_lds16(aSrc + (k0), lb);                              \
        gload_lds16(bSrc + (k0), lb + 4096);                       \
    } while (0)

#pragma unroll
    for (int pb = 0; pb < NBUF - 1; ++pb) STAGE(pb, pb * 32);
    if constexpr (NBUF == 3) asm volatile("s_waitcnt vmcnt(2)" ::: "memory");
    else                     asm volatile("s_waitcnt vmcnt(6)" ::: "memory");
    __builtin_amdgcn_s_barrier();
    __builtin_amdgcn_sched_barrier(0);

    int cur = 0, sb = NBUF - 1;
    for (int it = 0; it < NIT; ++it) {
        const bool more = (it + NBUF - 1) < NIT;
        if (more) STAGE(sb, (it + NBUF - 1) * 32);
        const bf16* bufA = LDS + cur * 8192;
        const bf16* bufB = bufA + 4096;
        bf16x8 af[4], bfr[2];
#pragma unroll
        for (int i = 0; i < 4; ++i)
            af[i] = *(const bf16x8*)&bufA[(wr * 64 + i * 16 + qr) * 32 + gx8];
#pragma unroll
        for (int j = 0; j < 2; ++j)
            bfr[j] = *(const bf16x8*)&bufB[(wc * 32 + j * 16 + qr) * 32 + gx8];
#pragma unroll
        for (int i = 0; i < 4; ++i)
#pragma unroll
            for (int j = 0; j < 2; ++j)
                acc[i][j] = MFMA16(af[i], bfr[j], acc[i][j]);
        if (more) {
            if constexpr (NBUF == 3) asm volatile("s_waitcnt vmcnt(2)" ::: "memory");
            else                     asm volatile("s_waitcnt vmcnt(6)" ::: "memory");
        } else {
            asm volatile("s_waitcnt vmcnt(0)" ::: "memory");
        }
        __builtin_amdgcn_s_barrier();
        __builtin_amdgcn_sched_barrier(0);
        cur = cur + 1 == NBUF ? 0 : cur + 1;
        sb  = sb + 1 == NBUF ? 0 : sb + 1;
    }
#undef STAGE

#pragma unroll
    for (int i = 0; i < 4; ++i) {
#pragma unroll
        for (int j = 0; j < 2; ++j) {
            const int rr0 = row0 + wr * 64 + i * 16 + g * 4;  // C/D row=(l>>4)*4+r
            const int cc  = col0 + wc * 32 + j * 16 + qr;     //     col=l&15
            if (EPI == 4) {
                if (cc < 1024) {                 // q
#pragma unroll
                    for (int r = 0; r < 4; ++r)
                        ((bf16*)Cout)[(size_t)(rr0 + r) * 1024 + cc] = (bf16)acc[i][j][r];
                } else if (cc < 1536) {          // k
#pragma unroll
                    for (int r = 0; r < 4; ++r)
                        ((bf16*)res)[(size_t)(rr0 + r) * 512 + (cc - 1024)] = (bf16)acc[i][j][r];
                } else {                         // v transposed bf16: Vt[b][kvh][d][s]
                    const int kv = cc - 1536, kvh = kv >> 6, d = kv & 63;
                    const int bb = rr0 >> 11, s0 = rr0 & 2047;
                    bf16 tmp[4];
#pragma unroll
                    for (int r = 0; r < 4; ++r) tmp[r] = (bf16)acc[i][j][r];
                    *(s16x4*)((bf16*)scale + (((size_t)bb * 8 + kvh) * 64 + d) * 2048 + s0) = *(s16x4*)tmp;
                }
            } else {
                float scv = 0.f;
                if (EPI == 1)
                    scv = f32 ? ((const float*)scale)[cc] : (float)((const bf16*)scale)[cc];
#pragma unroll
                for (int r = 0; r < 4; ++r) {
                    const size_t idx = (size_t)(rr0 + r) * N + cc;
                    float vv = acc[i][j][r];
                    if (EPI == 1) {
                        const float rv = (res_flv && f32) ? ((const float*)res)[idx]
                                                          : (float)((const bf16*)res)[idx];
                        vv = rv + vv * scv;
                    }
                    if (EPI == 3) {
                        const float uv = (float)((const bf16*)res)[idx];
                        vv = uv / (1.f + __expf(-uv)) * vv;
                    }
                    if (out_flv && f32) ((float*)Cout)[idx] = vv;
                    else                ((bf16*)Cout)[idx] = (bf16)vv;
                }
            }
        }
    }
}

// ---------------------------------------------------------------------------
// gemm_w13: fused SwiGLU up-projection (round-10 verified form).
// C = silu(A@B1^T) * (A@B3^T).  128x128 tile, BK=32, 8 waves, 3-buffer
// counted-vmcnt pipeline, shared A staging, column-ownership XCD remap
// (B1+B3 2MB/XCD L2-resident), swapped-operand MFMA -> s16x4 stores.
// ---------------------------------------------------------------------------
__global__ __launch_bounds__(512, 4)
void gemm_w13(const bf16* __restrict__ A, const bf16* __restrict__ B1,
              const bf16* __restrict__ B3, bf16* __restrict__ C,
              int M, int N, int K) {
    __shared__ bf16 LDS[3 * 12288];      // per buf: A 8KB | B1 8KB | B3 8KB
    const int t = threadIdx.x;
    const int wv = t >> 6, ln = t & 63;
    const int qr = ln & 15, g = ln >> 4;
    const int wr = wv >> 2, wc = wv & 3;
    int bx, by;
    {   // column-ownership XCD remap (grid 32x32, bijective)
        const int bid = blockIdx.y * gridDim.x + blockIdx.x;
        const int xcd = bid & 7, m = bid >> 3;
        bx = xcd * 4 + (m & 3);
        by = m >> 2;
    }
    const int row0 = by * 128, col0 = bx * 128;

    f32x4 acc1[4][2] = {}, acc3[4][2] = {};

    const int cx = ((t & 3) ^ ((t >> 2) & 3)) * 8;
    const bf16* aSrc  = A  + (size_t)(row0 + (t >> 2)) * K + cx;
    const bf16* b1Src = B1 + (size_t)(col0 + (t >> 2)) * K + cx;
    const bf16* b3Src = B3 + (size_t)(col0 + (t >> 2)) * K + cx;
    const int gx8 = (g ^ (qr & 3)) * 8;
    const int NIT = K >> 5;

#define STAGEW(bi, k0)                                             \
    do {                                                           \
        bf16* lb = LDS + (bi) * 12288 + wv * 512;                  \
        gload_lds16(aSrc + (k0), lb);                              \
        gload_lds16(b1Src + (k0), lb + 4096);                      \
        gload_lds16(b3Src + (k0), lb + 8192);                      \
    } while (0)

    STAGEW(0, 0);
    STAGEW(1, 32);
    asm volatile("s_waitcnt vmcnt(3)" ::: "memory");
    __builtin_amdgcn_s_barrier();
    __builtin_amdgcn_sched_barrier(0);

    int cur = 0, sb = 2;
    for (int it = 0; it < NIT; ++it) {
        const bool more = (it + 2) < NIT;
        if (more) STAGEW(sb, (it + 2) * 32);
        const bf16* bufA  = LDS + cur * 12288;
        const bf16* bufB1 = bufA + 4096;
        const bf16* bufB3 = bufA + 8192;
        bf16x8 af[4], b1f[2], b3f[2];
#pragma unroll
        for (int i = 0; i < 4; ++i)
            af[i] = *(const bf16x8*)&bufA[(wr * 64 + i * 16 + qr) * 32 + gx8];
#pragma unroll
        for (int j = 0; j < 2; ++j) {
            b1f[j] = *(const bf16x8*)&bufB1[(wc * 32 + j * 16 + qr) * 32 + gx8];
            b3f[j] = *(const bf16x8*)&bufB3[(wc * 32 + j * 16 + qr) * 32 + gx8];
        }
#pragma unroll
        for (int i = 0; i < 4; ++i)
#pragma unroll
            for (int j = 0; j < 2; ++j) {
                acc1[i][j] = MFMA16(b1f[j], af[i], acc1[i][j]);   // swapped
                acc3[i][j] = MFMA16(b3f[j], af[i], acc3[i][j]);   // swapped
            }
        if (more) asm volatile("s_waitcnt vmcnt(3)" ::: "memory");
        else      asm volatile("s_waitcnt vmcnt(0)" ::: "memory");
        __builtin_amdgcn_s_barrier();
        __builtin_amdgcn_sched_barrier(0);
        cur = cur == 2 ? 0 : cur + 1;
        sb  = sb  == 2 ? 0 : sb  + 1;
    }
#undef STAGEW

    // swapped C/D: row = row0+wr*64+i*16+qr, cols = col0+wc*32+j*16+g*4+r
#pragma unroll
    for (int i = 0; i < 4; ++i) {
        const int row = row0 + wr * 64 + i * 16 + qr;
#pragma unroll
        for (int j = 0; j < 2; ++j) {
            const int col = col0 + wc * 32 + j * 16 + g * 4;
            const size_t idx = (size_t)row * N + col;
            bf16 tmp[4];
#pragma unroll
            for (int r = 0; r < 4; ++r) {
                const float u1 = acc1[i][j][r];
                const float u3 = acc3[i][j][r];
                tmp[r] = (bf16)(u1 / (1.f + __expf(-u1)) * u3);
            }
            *(s16x4*)(C + idx) = *(s16x4*)tmp;
        }
    }
}

// ---------------------------------------------------------------------------
// Windowed-ALiBi GQA flash attention.  Round 12: 2 heads per block share the
// K/V staging stream.  Grid (S/64, KVH=8, B); 512 threads = 8 waves =
// 4 q-subtiles x 2 heads.  Threads 0-255 stage K, 256-511 stage V (one
// gload_lds per thread per tile; vmcnt(1) ledger, single barrier per tile).
// Compute body per wave identical to round 8/10.
// ---------------------------------------------------------------------------
__global__ __launch_bounds__(512)
void attn_kernel(const bf16* __restrict__ qn, const bf16* __restrict__ kn,
                 const bf16* __restrict__ vt, bf16* __restrict__ aout) {
    __shared__ bf16 SH[3 * 4096];      // buf: K [32 key][64 hd] | V [64 d][32 key]
    const int t = threadIdx.x, wv = t >> 6, ln = t & 63;
    const int qr = ln & 15, g = ln >> 4;
    const int kvh = blockIdx.y, b = blockIdx.z;
    const int hh = wv & 1, h = kvh * 2 + hh;
    const int qsub = wv >> 1;                        // 0..3
    const int q0blk = blockIdx.x * 64;
    const int qa = q0blk + qsub * 16 + qr;
    const float slope = exp2f(-0.5f * (float)(h + 1));

    const bf16* qrow = qn + ((size_t)(b * 2048 + qa)) * 1024 + h * 64;
    const bf16x8 qb0 = *(const bf16x8*)(qrow + g * 8);
    const bf16x8 qb1 = *(const bf16x8*)(qrow + 32 + g * 8);

    const bf16* kbase = kn + (size_t)b * 2048 * 512 + kvh * 64;
    const bf16* vbase = vt + ((size_t)(b * 8 + kvh) * 64) * 2048;

    // staging: waves 0-3 (t<256) stage K, waves 4-7 stage V; 1 load/thread
    const bool isK = t < 256;
    const int ts = t & 255;
    const int krow_l = ts >> 3;                      // 0..31
    const int kcsrc  = (ts & 7) ^ ((ts >> 3) & 7);
    const int vd     = ts >> 2;                      // 0..63
    const int vcsrc  = (ts & 3) ^ ((ts >> 2) & 3);
    const bf16* kgsrc = kbase + kcsrc * 8;
    const bf16* vgsrc = vbase + (size_t)vd * 2048;
    bf16* ldst = isK ? (SH + wv * 512) : (SH + 2048 + (wv - 4) * 512);

#define STAGE_T(kts, bi)                                           \
    do {                                                           \
        if (isK) {                                                 \
            int ksrc = (kts) + krow_l;                             \
            ksrc = ksrc > 2047 ? 2047 : ksrc;                      \
            gload_lds16(kgsrc + (size_t)ksrc * 512, ldst + (bi) * 4096); \
        } else {                                                   \
            int vsrc = (kts) + vcsrc * 8;                          \
            vsrc = vsrc > 2040 ? 2040 : vsrc;                      \
            gload_lds16(vgsrc + vsrc, ldst + (bi) * 4096);         \
        }                                                          \
    } while (0)

    STAGE_T(q0blk, 0);
    STAGE_T(q0blk + 32, 1);
    asm volatile("s_waitcnt vmcnt(1)" ::: "memory");
    __builtin_amdgcn_s_barrier();
    __builtin_amdgcn_sched_barrier(0);

    f32x4 o[4] = {};
    float mrun = -1e29f, lsum = 0.f;
    int cur = 0, sb = 2;

    for (int it = 0; it < 18; ++it) {
        const int kt = q0blk + it * 32;
        const bool more = (it + 2) < 18;
        if (more) STAGE_T(kt + 64, sb);
        const bf16* Kb = SH + cur * 4096;
        const bf16* Vb = Kb + 2048;

        f32x4 sc[2] = {f32x4{0, 0, 0, 0}, f32x4{0, 0, 0, 0}};
#pragma unroll
        for (int ks = 0; ks < 2; ++ks) {
            const int lrow = ks * 16 + qr;
            const int sw = (lrow & 7) * 8;
            sc[ks] = MFMA16(*(const bf16x8*)&Kb[lrow * 64 + (((g) * 8) ^ sw)],        qb0, sc[ks]);
            sc[ks] = MFMA16(*(const bf16x8*)&Kb[lrow * 64 + (((4 + g) * 8) ^ sw)],    qb1, sc[ks]);
        }
        float s[2][4], p[2][4];
        float tmax = -1e30f;
#pragma unroll
        for (int ks = 0; ks < 2; ++ks)
#pragma unroll
            for (int r = 0; r < 4; ++r) {
                const int key = kt + ks * 16 + g * 4 + r;
                const int dist = key - qa;
                const bool valid = (dist >= 0) && (dist <= 512) && (key < 2048);
                const float sv = valid ? sc[ks][r] * 0.125f - slope * (float)dist : -1e30f;
                s[ks][r] = sv;
                tmax = fmaxf(tmax, sv);
            }
        tmax = fmaxf(tmax, __shfl_xor(tmax, 16));
        tmax = fmaxf(tmax, __shfl_xor(tmax, 32));
        const float mnew = fmaxf(mrun, tmax);
        const float alpha = __expf(mrun - mnew);
        mrun = mnew;
        float ps = 0.f;
#pragma unroll
        for (int ks = 0; ks < 2; ++ks)
#pragma unroll
            for (int r = 0; r < 4; ++r) { p[ks][r] = __expf(s[ks][r] - mnew); ps += p[ks][r]; }
        lsum = lsum * alpha + ps;
#pragma unroll
        for (int fd = 0; fd < 4; ++fd) o[fd] *= alpha;

        bf16x8 pb;
#pragma unroll
        for (int j = 0; j < 8; ++j) {
            const int srcl = (((2 * g + (j >> 2)) & 3) << 4) | qr;
            const float v0 = __shfl(p[0][j & 3], srcl);
            const float v1 = __shfl(p[1][j & 3], srcl);
            pb[j] = (bf16)((g & 2) ? v1 : v0);
        }
#pragma unroll
        for (int fd = 0; fd < 4; ++fd) {
            const int d = fd * 16 + qr;
            const bf16x8 va = *(const bf16x8*)&Vb[d * 32 + ((g ^ (d & 3)) * 8)];
            o[fd] = MFMA16(va, pb, o[fd]);
        }

        if (more) asm volatile("s_waitcnt vmcnt(1)" ::: "memory");
        else      asm volatile("s_waitcnt vmcnt(0)" ::: "memory");
        __builtin_amdgcn_s_barrier();
        __builtin_amdgcn_sched_barrier(0);
        cur = cur == 2 ? 0 : cur + 1;
        sb  = sb  == 2 ? 0 : sb  + 1;
    }
#undef STAGE_T

    float lt = lsum + __shfl_xor(lsum, 16);
    lt += __shfl_xor(lt, 32);
    lt = fmaxf(lt, 1e-30f);
    const float inv = 1.f / lt;
    bf16* orow = aout + ((size_t)(b * 2048 + qa)) * 1024 + h * 64;
#pragma unroll
    for (int fd = 0; fd < 4; ++fd) {
        bf16 tmp[4];
#pragma unroll
        for (int r = 0; r < 4; ++r) tmp[r] = (bf16)(o[fd][r] * inv);
        *(s16x4*)(orow + fd * 16 + g * 4) = *(s16x4*)tmp;
    }
}

// ---------------------------------------------------------------------------
extern "C" void kernel_launch(void* const* d_in, const int* in_sizes, int n_in,
                              void* d_out, int out_size, void* d_ws, size_t ws_size,
                              hipStream_t stream) {
    int* flag = (int*)d_ws;
    bf16* base = (bf16*)d_ws + 64;
    bf16* h    = base;                // 4096*1024  (reused as h2)
    bf16* q    = h + 4194304;         // 4096*1024  (x1 after attn)
    bf16* kbuf = q + 4194304;         // 4096*512   (split-K partial base later)
    bf16* vtb  = kbuf + 2097152;      // 2*8*64*2048
    bf16* aout = vtb + 2097152;       // 4096*1024  (kbuf..aout = 2x4194304 span)
    bf16* u    = aout + 4194304;      // 4096*4096  (act)
    bf16* wcv  = u + 16777216;        // 15728640 converted weights (contiguous)

    bf16* woc = wcv + 2097152;
    bf16* w1c = wcv + 3145728;
    bf16* w3c = wcv + 7340032;
    bf16* w2c = wcv + 11534336;

    const dim3 blk(512);
    sniff_kernel<<<1, 256, 0, stream>>>((const unsigned short*)d_in[0], flag);
    convert_all_kernel<<<15360, 256, 0, stream>>>(
        d_in[1], d_in[2], d_in[3], d_in[4], d_in[9], d_in[11], d_in[10], wcv, flag);

    ln_kernel<<<4096, 128, 0, stream>>>(d_in[0], d_in[7], h, 1024, 1e-5f, flag, 1, 1);
    // fused QKV: B = [wq;wk;wv] rows, N=2048.  EPI4: Cout=q, res=kbuf, scale=vtb
    gemm2<4, 3, 0, 0><<<dim3(16, 32), blk, 0, stream>>>(h, wcv, q, kbuf, vtb, 4096, 2048, 1024, flag, 0, 0);
    // fused q-norm + k-norm
    ln_qk_kernel<<<8192, 128, 0, stream>>>(q, d_in[5], kbuf, d_in[6], flag);
    attn_kernel<<<dim3(32, 8, 2), dim3(512), 0, stream>>>(q, kbuf, vtb, aout);
    // x1 = x + (aout@wo^T)*attn_scale  -> q (bf16)
    gemm2<1, 3, 1, 0><<<dim3(8, 32), blk, 0, stream>>>(aout, woc, q, d_in[0], d_in[12], 4096, 1024, 1024, flag, 1, 0);
    ln_kernel<<<4096, 128, 0, stream>>>(q, d_in[8], h, 1024, 1e-5f, flag, 0, 1);
    // fused SwiGLU up: u = silu(h@w1^T) * (h@w3^T)
    gemm_w13<<<dim3(32, 32), blk, 0, stream>>>(h, w1c, w3c, u, 4096, 4096, 1024);
    // w2 split-K=2: partials (bf16) -> kbuf span, then reduce -> d_out
    gemm2<0, 5, 1, 1><<<dim3(8, 32, 2), blk, 0, stream>>>(u, w2c, kbuf, nullptr, nullptr, 4096, 1024, 4096, flag, 0, 0);
    reduce_k<<<2048, 256, 0, stream>>>(kbuf, q, d_in[13], d_out, flag);
}

// Round 13
// 243.821 us; speedup vs baseline: 1.0402x; 1.0126x over previous
//
#include <hip/hip_runtime.h>

// ---------------------------------------------------------------------------
// CodecTransformerLayer on MI355X (gfx950).  fp32 inputs (sniff-confirmed),
// bf16 internal compute.  Round 13: gemm_w13 deep-pipeline rework —
// BM=256 dual-B, 4 LDS slots (128KB), depth-2 counted vmcnt(4) (never 0 in
// steady state), 2 phases/unit with setprio-wrapped 16-MFMA clusters,
// 32 MFMA per barrier per wave.  Same vmcnt->barrier ledger as r3-r12.
// Everything else unchanged from round 12 (246.9us).
// B=2 S=2048 D=1024 H=16 KVH=8 hd=64 HIDDEN=4096 WINDOW=512
// ---------------------------------------------------------------------------

typedef __bf16 bf16;
typedef __attribute__((ext_vector_type(8))) __bf16 bf16x8;
typedef __attribute__((ext_vector_type(4))) float f32x4;
typedef __attribute__((ext_vector_type(4))) short s16x4;

#define MFMA16(a, b, c) __builtin_amdgcn_mfma_f32_16x16x32_bf16(a, b, c, 0, 0, 0)

__device__ __forceinline__ void gload_lds16(const bf16* g, bf16* l) {
    __builtin_amdgcn_global_load_lds(
        (const __attribute__((address_space(1))) unsigned int*)g,
        (__attribute__((address_space(3))) unsigned int*)l, 16, 0, 0);
}

// ---------------------------------------------------------------------------
__global__ void sniff_kernel(const unsigned short* __restrict__ x, int* __restrict__ flag) {
    __shared__ int s;
    if (threadIdx.x == 0) s = 0;
    __syncthreads();
    int bad = 0;
#pragma unroll
    for (int i = 0; i < 16; ++i) {
        const unsigned short u = x[threadIdx.x * 16 + i];
        const int e = (u >> 7) & 0xFF;
        if (e >= 135) bad = 1;
    }
    if (bad) atomicOr(&s, 1);
    __syncthreads();
    if (threadIdx.x == 0) flag[0] = s;
}

// ---------------------------------------------------------------------------
// Weight gather -> contiguous bf16.  seg map (elements):
// wq[0) wk[1048576) wv[1572864) wo[2097152) w1[3145728) w3[7340032)
// w2[11534336) end 15728640
// ---------------------------------------------------------------------------
__global__ void convert_all_kernel(const void* __restrict__ wq, const void* __restrict__ wk,
                                   const void* __restrict__ wv, const void* __restrict__ wo,
                                   const void* __restrict__ w1, const void* __restrict__ w3,
                                   const void* __restrict__ w2, bf16* __restrict__ dst,
                                   const int* __restrict__ flag) {
    const long e = ((long)blockIdx.x * 256 + threadIdx.x) * 4;
    const void* src; long off;
    if      (e < 1048576)  { src = wq; off = 0; }
    else if (e < 1572864)  { src = wk; off = 1048576; }
    else if (e < 2097152)  { src = wv; off = 1572864; }
    else if (e < 3145728)  { src = wo; off = 2097152; }
    else if (e < 7340032)  { src = w1; off = 3145728; }
    else if (e < 11534336) { src = w3; off = 7340032; }
    else                   { src = w2; off = 11534336; }
    if (flag[0] != 0) {
        const f32x4 v = *(const f32x4*)((const float*)src + (e - off));
        bf16 tmp[4];
#pragma unroll
        for (int j = 0; j < 4; ++j) tmp[j] = (bf16)v[j];
        *(s16x4*)(dst + e) = *(s16x4*)tmp;
    } else {
        *(s16x4*)(dst + e) = *(const s16x4*)((const short*)src + (e - off));
    }
}

// ---------------------------------------------------------------------------
// LayerNorm row body (128 threads per row).
// ---------------------------------------------------------------------------
__device__ __forceinline__ void ln_row(const void* in, const void* w, bf16* out,
                                       int row, int W, float eps, bool f32,
                                       int in_flv, int w_flv) {
    const int t = threadIdx.x;
    const int nch = W >> 3;
    const bool act = t < nch;
    float v[8];
    float s = 0.f, s2 = 0.f;
    if (act) {
        if (in_flv && f32) {
            const float* rp = (const float*)in + (size_t)row * W + t * 8;
            const f32x4 a = *(const f32x4*)rp, b = *(const f32x4*)(rp + 4);
#pragma unroll
            for (int j = 0; j < 4; ++j) { v[j] = a[j]; v[4 + j] = b[j]; }
        } else {
            const bf16x8 xv = *(const bf16x8*)((const bf16*)in + (size_t)row * W + t * 8);
#pragma unroll
            for (int j = 0; j < 8; ++j) v[j] = (float)xv[j];
        }
#pragma unroll
        for (int j = 0; j < 8; ++j) { s += v[j]; s2 += v[j] * v[j]; }
    }
#pragma unroll
    for (int off = 32; off; off >>= 1) { s += __shfl_xor(s, off); s2 += __shfl_xor(s2, off); }
    __shared__ float red[4];
    if ((t & 63) == 0) { red[(t >> 6) * 2] = s; red[(t >> 6) * 2 + 1] = s2; }
    __syncthreads();
    const float fs = red[0] + red[2], fs2 = red[1] + red[3];
    const float inw = 1.f / (float)W;
    const float mean = fs * inw;
    const float var = fs2 * inw - mean * mean;
    const float rstd = rsqrtf(var + eps);
    if (act) {
        float wv8[8];
        if (w_flv && f32) {
            const float* wp = (const float*)w + t * 8;
            const f32x4 a = *(const f32x4*)wp, b = *(const f32x4*)(wp + 4);
#pragma unroll
            for (int j = 0; j < 4; ++j) { wv8[j] = a[j]; wv8[4 + j] = b[j]; }
        } else {
            const bf16x8 ww = *(const bf16x8*)((const bf16*)w + t * 8);
#pragma unroll
            for (int j = 0; j < 8; ++j) wv8[j] = (float)ww[j];
        }
        bf16x8 ov;
#pragma unroll
        for (int j = 0; j < 8; ++j) ov[j] = (bf16)((v[j] - mean) * rstd * wv8[j]);
        *(bf16x8*)(out + (size_t)row * W + t * 8) = ov;
    }
}

__global__ void ln_kernel(const void* __restrict__ in, const void* __restrict__ w,
                          bf16* __restrict__ out, int W, float eps,
                          const int* __restrict__ flag, int in_flv, int w_flv) {
    ln_row(in, w, out, blockIdx.x, W, eps, flag[0] != 0, in_flv, w_flv);
}

// fused q-norm (rows 0..4095, W=1024) + k-norm (rows 4096..8191, W=512)
__global__ void ln_qk_kernel(bf16* __restrict__ q, const void* __restrict__ qw,
                             bf16* __restrict__ kbuf, const void* __restrict__ kw,
                             const int* __restrict__ flag) {
    const bool f32 = flag[0] != 0;
    if (blockIdx.x < 4096)
        ln_row(q, qw, q, blockIdx.x, 1024, 1e-6f, f32, 0, 1);
    else
        ln_row(kbuf, kw, kbuf, blockIdx.x - 4096, 512, 1e-6f, f32, 0, 1);
}

// ---------------------------------------------------------------------------
// Split-K reduce: out = x1 + (p0+p1)*scale[col].  p bf16 [2][4096][1024].
// ---------------------------------------------------------------------------
__global__ void reduce_k(const bf16* __restrict__ p, const bf16* __restrict__ x1,
                         const void* __restrict__ scale, void* __restrict__ out,
                         const int* __restrict__ flag) {
    const bool f32 = flag[0] != 0;
    const size_t i8 = ((size_t)blockIdx.x * 256 + threadIdx.x) * 8;
    const int col = (int)(i8 & 1023);
    const bf16x8 a = *(const bf16x8*)(p + i8);
    const bf16x8 b = *(const bf16x8*)(p + 4194304 + i8);
    const bf16x8 r = *(const bf16x8*)(x1 + i8);
    float sc8[8];
    if (f32) {
        const f32x4 s0 = *(const f32x4*)((const float*)scale + col);
        const f32x4 s1 = *(const f32x4*)((const float*)scale + col + 4);
#pragma unroll
        for (int j = 0; j < 4; ++j) { sc8[j] = s0[j]; sc8[4 + j] = s1[j]; }
    } else {
        const bf16x8 sb = *(const bf16x8*)((const bf16*)scale + col);
#pragma unroll
        for (int j = 0; j < 8; ++j) sc8[j] = (float)sb[j];
    }
    float o[8];
#pragma unroll
    for (int j = 0; j < 8; ++j)
        o[j] = (float)r[j] + ((float)a[j] + (float)b[j]) * sc8[j];
    if (f32) {
        f32x4 o0, o1;
#pragma unroll
        for (int j = 0; j < 4; ++j) { o0[j] = o[j]; o1[j] = o[4 + j]; }
        *(f32x4*)((float*)out + i8) = o0;
        *(f32x4*)((float*)out + i8 + 4) = o1;
    } else {
        bf16x8 ov;
#pragma unroll
        for (int j = 0; j < 8; ++j) ov[j] = (bf16)o[j];
        *(bf16x8*)((bf16*)out + i8) = ov;
    }
}

// ---------------------------------------------------------------------------
// Pipelined GEMM  C[M,N] = A[M,K] * B[N,K]^T.  128x128 tile, BK=32, 8 waves
// (2Mx4N), NBUF-deep counted-vmcnt pipeline, chunk-XOR LDS swizzle.
// SWZ=1: row-ownership XCD remap.  SPLITK=1: blockIdx.z selects K half.
// Epilogues: 0 plain; 1 res+acc*scale; 3 silu(res)*acc; 4 QKV split.
// ---------------------------------------------------------------------------
template <int EPI, int NBUF, int SWZ, int SPLITK>
__global__ __launch_bounds__(512, 4)
void gemm2(const bf16* __restrict__ A, const bf16* __restrict__ B,
           void* __restrict__ Cout, const void* __restrict__ res,
           const void* __restrict__ scale, int M, int N, int K,
           const int* __restrict__ flag, int res_flv, int out_flv) {
    __shared__ bf16 LDS[NBUF * 8192];
    const bool f32 = flag[0] != 0;
    const int t = threadIdx.x;
    const int wv = t >> 6, ln = t & 63;
    const int qr = ln & 15, g = ln >> 4;
    const int wr = wv >> 2, wc = wv & 3;
    int bx = blockIdx.x, by = blockIdx.y;
    if (SWZ) {   // row-ownership remap (round-10 verified)
        const int bid = by * gridDim.x + bx;
        const int g8 = bid & 7, m = bid >> 3;
        bx = m % gridDim.x;
        by = g8 + 8 * (m / gridDim.x);
    }
    const int row0 = by * 128, col0 = bx * 128;

    const int Koff = SPLITK ? (int)blockIdx.z * (K >> 1) : 0;
    const int Keff = SPLITK ? (K >> 1) : K;
    if (SPLITK) Cout = (void*)((bf16*)Cout + (size_t)blockIdx.z * ((size_t)M * N));

    f32x4 acc[4][2] = {};

    const int cx = ((t & 3) ^ ((t >> 2) & 3)) * 8;
    const bf16* aSrc = A + (size_t)(row0 + (t >> 2)) * K + Koff + cx;
    const bf16* bSrc = B + (size_t)(col0 + (t >> 2)) * K + Koff + cx;
    const int gx8 = (g ^ (qr & 3)) * 8;              // swizzled read chunk
    const int NIT = Keff >> 5;

#define STAGE(bi, k0)                                              \
    do {                                                           \
        bf16* lb = LDS + (bi) * 8192 + wv * 512;                   \
        gload_lds16(aSrc + (k0), lb);                              \
        gload_lds16(bSrc + (k0), lb + 4096);                       \
    } while (0)

#pragma unroll
    for (int pb = 0; pb < NBUF - 1; ++pb) STAGE(pb, pb * 32);
    if constexpr (NBUF == 3) asm volatile("s_waitcnt vmcnt(2)" ::: "memory");
    else                     asm volatile("s_waitcnt vmcnt(6)" ::: "memory");
    __builtin_amdgcn_s_barrier();
    __builtin_amdgcn_sched_barrier(0);

    int cur = 0, sb = NBUF - 1;
    for (int it = 0; it < NIT; ++it) {
        const bool more = (it + NBUF - 1) < NIT;
        if (more) STAGE(sb, (it + NBUF - 1) * 32);
        const bf16* bufA = LDS + cur * 8192;
        const bf16* bufB = bufA + 4096;
        bf16x8 af[4], bfr[2];
#pragma unroll
        for (int i = 0; i < 4; ++i)
            af[i] = *(const bf16x8*)&bufA[(wr * 64 + i * 16 + qr) * 32 + gx8];
#pragma unroll
        for (int j = 0; j < 2; ++j)
            bfr[j] = *(const bf16x8*)&bufB[(wc * 32 + j * 16 + qr) * 32 + gx8];
#pragma unroll
        for (int i = 0; i < 4; ++i)
#pragma unroll
            for (int j = 0; j < 2; ++j)
                acc[i][j] = MFMA16(af[i], bfr[j], acc[i][j]);
        if (more) {
            if constexpr (NBUF == 3) asm volatile("s_waitcnt vmcnt(2)" ::: "memory");
            else                     asm volatile("s_waitcnt vmcnt(6)" ::: "memory");
        } else {
            asm volatile("s_waitcnt vmcnt(0)" ::: "memory");
        }
        __builtin_amdgcn_s_barrier();
        __builtin_amdgcn_sched_barrier(0);
        cur = cur + 1 == NBUF ? 0 : cur + 1;
        sb  = sb + 1 == NBUF ? 0 : sb + 1;
    }
#undef STAGE

#pragma unroll
    for (int i = 0; i < 4; ++i) {
#pragma unroll
        for (int j = 0; j < 2; ++j) {
            const int rr0 = row0 + wr * 64 + i * 16 + g * 4;  // C/D row=(l>>4)*4+r
            const int cc  = col0 + wc * 32 + j * 16 + qr;     //     col=l&15
            if (EPI == 4) {
                if (cc < 1024) {                 // q
#pragma unroll
                    for (int r = 0; r < 4; ++r)
                        ((bf16*)Cout)[(size_t)(rr0 + r) * 1024 + cc] = (bf16)acc[i][j][r];
                } else if (cc < 1536) {          // k
#pragma unroll
                    for (int r = 0; r < 4; ++r)
                        ((bf16*)res)[(size_t)(rr0 + r) * 512 + (cc - 1024)] = (bf16)acc[i][j][r];
                } else {                         // v transposed bf16: Vt[b][kvh][d][s]
                    const int kv = cc - 1536, kvh = kv >> 6, d = kv & 63;
                    const int bb = rr0 >> 11, s0 = rr0 & 2047;
                    bf16 tmp[4];
#pragma unroll
                    for (int r = 0; r < 4; ++r) tmp[r] = (bf16)acc[i][j][r];
                    *(s16x4*)((bf16*)scale + (((size_t)bb * 8 + kvh) * 64 + d) * 2048 + s0) = *(s16x4*)tmp;
                }
            } else {
                float scv = 0.f;
                if (EPI == 1)
                    scv = f32 ? ((const float*)scale)[cc] : (float)((const bf16*)scale)[cc];
#pragma unroll
                for (int r = 0; r < 4; ++r) {
                    const size_t idx = (size_t)(rr0 + r) * N + cc;
                    float vv = acc[i][j][r];
                    if (EPI == 1) {
                        const float rv = (res_flv && f32) ? ((const float*)res)[idx]
                                                          : (float)((const bf16*)res)[idx];
                        vv = rv + vv * scv;
                    }
                    if (EPI == 3) {
                        const float uv = (float)((const bf16*)res)[idx];
                        vv = uv / (1.f + __expf(-uv)) * vv;
                    }
                    if (out_flv && f32) ((float*)Cout)[idx] = vv;
                    else                ((bf16*)Cout)[idx] = (bf16)vv;
                }
            }
        }
    }
}

// ---------------------------------------------------------------------------
// gemm_w13 (round 13): deep-pipelined fused SwiGLU up-projection.
// C = silu(A@B1^T) * (A@B3^T).  Block = 256 rows x 128 cols (per matrix).
// Unit = 32-K slab {A 16KB | B1 8KB | B3 8KB} staged with 4 gload_lds/thread
// into one of 4 LDS slots (128KB total); depth-2 prefetch, vmcnt(4) at unit
// boundary (never 0 until tail), ONE barrier/unit (vmcnt-then-barrier ledger
// as r3-r12).  8 waves as 4Mx2N (wave = 64x64 per matrix; acc 4x4 x2).
// Two phases/unit: {stage 2, read af+b1f, setprio, 16 MFMA acc1} then
// {stage 2, read b3f, setprio, 16 MFMA acc3} -> 32 MFMA per barrier.
// Column-ownership XCD remap (B1+B3 slice 2MB/XCD, L2-resident).
// Swapped-operand MFMA -> s16x4 stores.
// ---------------------------------------------------------------------------
__global__ __launch_bounds__(512, 2)
void gemm_w13(const bf16* __restrict__ A, const bf16* __restrict__ B1,
              const bf16* __restrict__ B3, bf16* __restrict__ C,
              int M, int N, int K) {
    __shared__ bf16 LDS[4 * 16384];      // 4 slots x 32KB {A 16K | B1 8K | B3 8K}
    const int t = threadIdx.x;
    const int wv = t >> 6, ln = t & 63;
    const int qr = ln & 15, g = ln >> 4;
    const int wr = wv >> 1, wc = wv & 1;         // wave grid 4M x 2N
    int bx, by;
    {   // column-ownership XCD remap (grid 32x16 = 512, bijective)
        const int bid = blockIdx.y * gridDim.x + blockIdx.x;
        const int xcd = bid & 7, m = bid >> 3;   // m in 0..63
        bx = xcd * 4 + (m & 3);                  // 4 col panels per XCD
        by = m >> 2;                             // 0..15
    }
    const int row0 = by * 256, col0 = bx * 128;

    f32x4 acc1[4][4] = {}, acc3[4][4] = {};

    const int cx = ((t & 3) ^ ((t >> 2) & 3)) * 8;   // proven swizzle pair
    const bf16* aSrc0 = A  + (size_t)(row0 + (t >> 2)) * K + cx;
    const bf16* aSrc1 = A  + (size_t)(row0 + 128 + (t >> 2)) * K + cx;
    const bf16* b1Src = B1 + (size_t)(col0 + (t >> 2)) * K + cx;
    const bf16* b3Src = B3 + (size_t)(col0 + (t >> 2)) * K + cx;
    const int gx8 = (g ^ (qr & 3)) * 8;
    const int NU = K >> 5;                       // 32 units

    // per-issue LDS dests (wave-uniform base; gload writes base + lane*16B)
#define ST_A0(s, k0) gload_lds16(aSrc0 + (k0), LDS + (s) * 16384 + wv * 512)
#define ST_A1(s, k0) gload_lds16(aSrc1 + (k0), LDS + (s) * 16384 + 4096 + wv * 512)
#define ST_B1(s, k0) gload_lds16(b1Src + (k0), LDS + (s) * 16384 + 8192 + wv * 512)
#define ST_B3(s, k0) gload_lds16(b3Src + (k0), LDS + (s) * 16384 + 12288 + wv * 512)

    // prologue: stage units 0 and 1 (8 issues), wait own unit-0 (vmcnt 4),
    // barrier closes the cross-wave gap.
    ST_A0(0, 0);  ST_A1(0, 0);  ST_B1(0, 0);  ST_B3(0, 0);
    ST_A0(1, 32); ST_A1(1, 32); ST_B1(1, 32); ST_B3(1, 32);
    asm volatile("s_waitcnt vmcnt(4)" ::: "memory");
    __builtin_amdgcn_s_barrier();
    __builtin_amdgcn_sched_barrier(0);

    for (int u = 0; u < NU; ++u) {
        const int su = u & 3;
        const bf16* slot = LDS + su * 16384;
        const bool more = (u + 2) < NU;
        const int kn = (u + 2) * 32;
        const int sn = (u + 2) & 3;

        // ---- phase 1: stage 2, read A + B1, 16 MFMA into acc1 --------------
        if (more) { ST_A0(sn, kn); ST_A1(sn, kn); }
        bf16x8 af[4], bf1[4];
#pragma unroll
        for (int i = 0; i < 4; ++i)
            af[i] = *(const bf16x8*)&slot[(wr * 64 + i * 16 + qr) * 32 + gx8];
#pragma unroll
        for (int j = 0; j < 4; ++j)
            bf1[j] = *(const bf16x8*)&slot[8192 + (wc * 64 + j * 16 + qr) * 32 + gx8];
        __builtin_amdgcn_s_setprio(1);
#pragma unroll
        for (int i = 0; i < 4; ++i)
#pragma unroll
            for (int j = 0; j < 4; ++j)
                acc1[i][j] = MFMA16(bf1[j], af[i], acc1[i][j]);   // swapped
        __builtin_amdgcn_s_setprio(0);

        // ---- phase 2: stage 2, read B3 (reuse af), 16 MFMA into acc3 -------
        if (more) { ST_B1(sn, kn); ST_B3(sn, kn); }
        bf16x8 bf3[4];
#pragma unroll
        for (int j = 0; j < 4; ++j)
            bf3[j] = *(const bf16x8*)&slot[12288 + (wc * 64 + j * 16 + qr) * 32 + gx8];
        __builtin_amdgcn_s_setprio(1);
#pragma unroll
        for (int i = 0; i < 4; ++i)
#pragma unroll
            for (int j = 0; j < 4; ++j)
                acc3[i][j] = MFMA16(bf3[j], af[i], acc3[i][j]);   // swapped
        __builtin_amdgcn_s_setprio(0);

        // ---- unit boundary: counted wait (own loads), then barrier ---------
        if (more) asm volatile("s_waitcnt vmcnt(4)" ::: "memory");
        else      asm volatile("s_waitcnt vmcnt(0)" ::: "memory");
        __builtin_amdgcn_s_barrier();
        __builtin_amdgcn_sched_barrier(0);
    }
#undef ST_A0
#undef ST_A1
#undef ST_B1
#undef ST_B3

    // swapped C/D: row = row0+wr*64+i*16+qr, cols = col0+wc*64+j*16+g*4+r
#pragma unroll
    for (int i = 0; i < 4; ++i) {
        const int row = row0 + wr * 64 + i * 16 + qr;
#pragma unroll
        for (int j = 0; j < 4; ++j) {
            const int col = col0 + wc * 64 + j * 16 + g * 4;
            const size_t idx = (size_t)row * N + col;
            bf16 tmp[4];
#pragma unroll
            for (int r = 0; r < 4; ++r) {
                const float u1 = acc1[i][j][r];
                const float u3 = acc3[i][j][r];
                tmp[r] = (bf16)(u1 / (1.f + __expf(-u1)) * u3);
            }
            *(s16x4*)(C + idx) = *(s16x4*)tmp;
        }
    }
}

// ---------------------------------------------------------------------------
// Windowed-ALiBi GQA flash attention (round-12 form: 2 heads/block share the
// K/V staging stream; 512 thr = 8 waves = 4 q-sub x 2 heads; K-stagers /
// V-stagers split; vmcnt(1) ledger, single barrier per tile).
// ---------------------------------------------------------------------------
__global__ __launch_bounds__(512)
void attn_kernel(const bf16* __restrict__ qn, const bf16* __restrict__ kn,
                 const bf16* __restrict__ vt, bf16* __restrict__ aout) {
    __shared__ bf16 SH[3 * 4096];      // buf: K [32 key][64 hd] | V [64 d][32 key]
    const int t = threadIdx.x, wv = t >> 6, ln = t & 63;
    const int qr = ln & 15, g = ln >> 4;
    const int kvh = blockIdx.y, b = blockIdx.z;
    const int hh = wv & 1, h = kvh * 2 + hh;
    const int qsub = wv >> 1;
    const int q0blk = blockIdx.x * 64;
    const int qa = q0blk + qsub * 16 + qr;
    const float slope = exp2f(-0.5f * (float)(h + 1));

    const bf16* qrow = qn + ((size_t)(b * 2048 + qa)) * 1024 + h * 64;
    const bf16x8 qb0 = *(const bf16x8*)(qrow + g * 8);
    const bf16x8 qb1 = *(const bf16x8*)(qrow + 32 + g * 8);

    const bf16* kbase = kn + (size_t)b * 2048 * 512 + kvh * 64;
    const bf16* vbase = vt + ((size_t)(b * 8 + kvh) * 64) * 2048;

    const bool isK = t < 256;
    const int ts = t & 255;
    const int krow_l = ts >> 3;
    const int kcsrc  = (ts & 7) ^ ((ts >> 3) & 7);
    const int vd     = ts >> 2;
    const int vcsrc  = (ts & 3) ^ ((ts >> 2) & 3);
    const bf16* kgsrc = kbase + kcsrc * 8;
    const bf16* vgsrc = vbase + (size_t)vd * 2048;
    bf16* ldst = isK ? (SH + wv * 512) : (SH + 2048 + (wv - 4) * 512);

#define STAGE_T(kts, bi)                                           \
    do {                                                           \
        if (isK) {                                                 \
            int ksrc = (kts) + krow_l;                             \
            ksrc = ksrc > 2047 ? 2047 : ksrc;                      \
            gload_lds16(kgsrc + (size_t)ksrc * 512, ldst + (bi) * 4096); \
        } else {                                                   \
            int vsrc = (kts) + vcsrc * 8;                          \
            vsrc = vsrc > 2040 ? 2040 : vsrc;                      \
            gload_lds16(vgsrc + vsrc, ldst + (bi) * 4096);         \
        }                                                          \
    } while (0)

    STAGE_T(q0blk, 0);
    STAGE_T(q0blk + 32, 1);
    asm volatile("s_waitcnt vmcnt(1)" ::: "memory");
    __builtin_amdgcn_s_barrier();
    __builtin_amdgcn_sched_barrier(0);

    f32x4 o[4] = {};
    float mrun = -1e29f, lsum = 0.f;
    int cur = 0, sb = 2;

    for (int it = 0; it < 18; ++it) {
        const int kt = q0blk + it * 32;
        const bool more = (it + 2) < 18;
        if (more) STAGE_T(kt + 64, sb);
        const bf16* Kb = SH + cur * 4096;
        const bf16* Vb = Kb + 2048;

        f32x4 sc[2] = {f32x4{0, 0, 0, 0}, f32x4{0, 0, 0, 0}};
#pragma unroll
        for (int ks = 0; ks < 2; ++ks) {
            const int lrow = ks * 16 + qr;
            const int sw = (lrow & 7) * 8;
            sc[ks] = MFMA16(*(const bf16x8*)&Kb[lrow * 64 + (((g) * 8) ^ sw)],        qb0, sc[ks]);
            sc[ks] = MFMA16(*(const bf16x8*)&Kb[lrow * 64 + (((4 + g) * 8) ^ sw)],    qb1, sc[ks]);
        }
        float s[2][4], p[2][4];
        float tmax = -1e30f;
#pragma unroll
        for (int ks = 0; ks < 2; ++ks)
#pragma unroll
            for (int r = 0; r < 4; ++r) {
                const int key = kt + ks * 16 + g * 4 + r;
                const int dist = key - qa;
                const bool valid = (dist >= 0) && (dist <= 512) && (key < 2048);
                const float sv = valid ? sc[ks][r] * 0.125f - slope * (float)dist : -1e30f;
                s[ks][r] = sv;
                tmax = fmaxf(tmax, sv);
            }
        tmax = fmaxf(tmax, __shfl_xor(tmax, 16));
        tmax = fmaxf(tmax, __shfl_xor(tmax, 32));
        const float mnew = fmaxf(mrun, tmax);
        const float alpha = __expf(mrun - mnew);
        mrun = mnew;
        float ps = 0.f;
#pragma unroll
        for (int ks = 0; ks < 2; ++ks)
#pragma unroll
            for (int r = 0; r < 4; ++r) { p[ks][r] = __expf(s[ks][r] - mnew); ps += p[ks][r]; }
        lsum = lsum * alpha + ps;
#pragma unroll
        for (int fd = 0; fd < 4; ++fd) o[fd] *= alpha;

        bf16x8 pb;
#pragma unroll
        for (int j = 0; j < 8; ++j) {
            const int srcl = (((2 * g + (j >> 2)) & 3) << 4) | qr;
            const float v0 = __shfl(p[0][j & 3], srcl);
            const float v1 = __shfl(p[1][j & 3], srcl);
            pb[j] = (bf16)((g & 2) ? v1 : v0);
        }
#pragma unroll
        for (int fd = 0; fd < 4; ++fd) {
            const int d = fd * 16 + qr;
            const bf16x8 va = *(const bf16x8*)&Vb[d * 32 + ((g ^ (d & 3)) * 8)];
            o[fd] = MFMA16(va, pb, o[fd]);
        }

        if (more) asm volatile("s_waitcnt vmcnt(1)" ::: "memory");
        else      asm volatile("s_waitcnt vmcnt(0)" ::: "memory");
        __builtin_amdgcn_s_barrier();
        __builtin_amdgcn_sched_barrier(0);
        cur = cur == 2 ? 0 : cur + 1;
        sb  = sb  == 2 ? 0 : sb  + 1;
    }
#undef STAGE_T

    float lt = lsum + __shfl_xor(lsum, 16);
    lt += __shfl_xor(lt, 32);
    lt = fmaxf(lt, 1e-30f);
    const float inv = 1.f / lt;
    bf16* orow = aout + ((size_t)(b * 2048 + qa)) * 1024 + h * 64;
#pragma unroll
    for (int fd = 0; fd < 4; ++fd) {
        bf16 tmp[4];
#pragma unroll
        for (int r = 0; r < 4; ++r) tmp[r] = (bf16)(o[fd][r] * inv);
        *(s16x4*)(orow + fd * 16 + g * 4) = *(s16x4*)tmp;
    }
}

// ---------------------------------------------------------------------------
extern "C" void kernel_launch(void* const* d_in, const int* in_sizes, int n_in,
                              void* d_out, int out_size, void* d_ws, size_t ws_size,
                              hipStream_t stream) {
    int* flag = (int*)d_ws;
    bf16* base = (bf16*)d_ws + 64;
    bf16* h    = base;                // 4096*1024  (reused as h2)
    bf16* q    = h + 4194304;         // 4096*1024  (x1 after attn)
    bf16* kbuf = q + 4194304;         // 4096*512   (split-K partial base later)
    bf16* vtb  = kbuf + 2097152;      // 2*8*64*2048
    bf16* aout = vtb + 2097152;       // 4096*1024  (kbuf..aout = 2x4194304 span)
    bf16* u    = aout + 4194304;      // 4096*4096  (act)
    bf16* wcv  = u + 16777216;        // 15728640 converted weights (contiguous)

    bf16* woc = wcv + 2097152;
    bf16* w1c = wcv + 3145728;
    bf16* w3c = wcv + 7340032;
    bf16* w2c = wcv + 11534336;

    const dim3 blk(512);
    sniff_kernel<<<1, 256, 0, stream>>>((const unsigned short*)d_in[0], flag);
    convert_all_kernel<<<15360, 256, 0, stream>>>(
        d_in[1], d_in[2], d_in[3], d_in[4], d_in[9], d_in[11], d_in[10], wcv, flag);

    ln_kernel<<<4096, 128, 0, stream>>>(d_in[0], d_in[7], h, 1024, 1e-5f, flag, 1, 1);
    // fused QKV: B = [wq;wk;wv] rows, N=2048.  EPI4: Cout=q, res=kbuf, scale=vtb
    gemm2<4, 3, 0, 0><<<dim3(16, 32), blk, 0, stream>>>(h, wcv, q, kbuf, vtb, 4096, 2048, 1024, flag, 0, 0);
    // fused q-norm + k-norm
    ln_qk_kernel<<<8192, 128, 0, stream>>>(q, d_in[5], kbuf, d_in[6], flag);
    attn_kernel<<<dim3(32, 8, 2), dim3(512), 0, stream>>>(q, kbuf, vtb, aout);
    // x1 = x + (aout@wo^T)*attn_scale  -> q (bf16)
    gemm2<1, 3, 1, 0><<<dim3(8, 32), blk, 0, stream>>>(aout, woc, q, d_in[0], d_in[12], 4096, 1024, 1024, flag, 1, 0);
    ln_kernel<<<4096, 128, 0, stream>>>(q, d_in[8], h, 1024, 1e-5f, flag, 0, 1);
    // fused SwiGLU up: u = silu(h@w1^T) * (h@w3^T)   (deep-pipelined 256x128)
    gemm_w13<<<dim3(32, 16), blk, 0, stream>>>(h, w1c, w3c, u, 4096, 4096, 1024);
    // w2 split-K=2: partials (bf16) -> kbuf span, then reduce -> d_out
    gemm2<0, 5, 1, 1><<<dim3(8, 32, 2), blk, 0, stream>>>(u, w2c, kbuf, nullptr, nullptr, 4096, 1024, 4096, flag, 0, 0);
    reduce_k<<<2048, 256, 0, stream>>>(kbuf, q, d_in[13], d_out, flag);
}